// Round 10
// baseline (264.674 us; speedup 1.0000x reference)
//
#include <hip/hip_runtime.h>
#include <hip/hip_bf16.h>
#include <stdint.h>

// Batched NT-GEMM: out[b,i,j] = sum_d m1[b,i,d] * m2[b,j,d]
// B=16, M=N=2048, K=256, fp32 in/out; f16 MFMA compute.
//
// Round 10: NO-LDS, NO-BARRIER direct-fragment kernel.
//   R9's profile: MfmaUtil 8.9%, VALUBusy 7.3% (85% wait), 6.3M LDS bank
//   conflicts, FETCH 36MB (reads L3-absorbed; kernel is write-dominated).
//   LDS round-trip existed only to convert fp32->f16 — but each fragment
//   element is consumed by exactly ONE lane, so load it straight from
//   global (L1/L2-resident tile) in MFMA layout and pkrtz in-register:
//     lane l, frag m: A[brow+wr+m*16+(l&15)][k0+(l>>4)*8 .. +8]  (2x dwordx4)
//   Removes: all ds_write/ds_read (~1130 cyc/K-step/CU), all s_barrier
//   (8-wave lockstep), all forced waitcnt drains. Waves free-run; the
//   compiler software-pipelines the unrolled K-loop with counted vmcnt.
//   L1 catches the 2x intra-block fragment sharing (w0/w1 same A rows,
//   w0/w2 same B rows); L2 sees ~17 TB/s << 34.5 ceiling.

typedef _Float16 f16x8 __attribute__((ext_vector_type(8)));
typedef _Float16 f16x2 __attribute__((ext_vector_type(2)));
typedef float f32x4 __attribute__((ext_vector_type(4)));

#define NB 16
#define DM 2048
#define DN 2048
#define DK 256
#define BM 128
#define BN 128
#define BK 32
#define NT (DK / BK)                    // 8 K-steps
#define NWG (NB * (DM/BM) * (DN/BN))    // 4096 blocks

__global__ __launch_bounds__(256, 2) void fused_gemm(const float* __restrict__ A,
                                                     const float* __restrict__ B,
                                                     float* __restrict__ C) {
    const int t = threadIdx.x;

    // XCD swizzle (NWG % 8 == 0 -> bijective); bx fastest within a chunk.
    const int bid = blockIdx.x;
    const int swz = (bid & 7) * (NWG / 8) + (bid >> 3);
    const int b    = swz >> 8;          // 256 blocks per batch
    const int rem  = swz & 255;
    const int brow = (rem >> 4) << 7;   // * BM
    const int bcol = (rem & 15) << 7;   // * BN

    const int w    = t >> 6;
    const int l    = t & 63;
    const int wr   = (w >> 1) * 64;     // wave row offset in tile
    const int wc   = (w & 1) * 64;      // wave col offset in tile
    const int lrow = l & 15;
    const int lko  = (l >> 4) * 8;      // k-offset of lane's 8 elements

    // Per-lane fragment base pointers (row = this lane's row in frag m=0).
    const float* Ab = A + (size_t)b * DM * DK + (size_t)(brow + wr + lrow) * DK + lko;
    const float* Bb = B + (size_t)b * DN * DK + (size_t)(bcol + wc + lrow) * DK + lko;

    f32x4 acc[4][4] = {};

    auto cvt8 = [](const float4& lo, const float4& hi) -> f16x8 {
        f16x2 p0 = __builtin_bit_cast(f16x2, __builtin_amdgcn_cvt_pkrtz(lo.x, lo.y));
        f16x2 p1 = __builtin_bit_cast(f16x2, __builtin_amdgcn_cvt_pkrtz(lo.z, lo.w));
        f16x2 p2 = __builtin_bit_cast(f16x2, __builtin_amdgcn_cvt_pkrtz(hi.x, hi.y));
        f16x2 p3 = __builtin_bit_cast(f16x2, __builtin_amdgcn_cvt_pkrtz(hi.z, hi.w));
        return f16x8{ p0[0], p0[1], p1[0], p1[1], p2[0], p2[1], p3[0], p3[1] };
    };

#pragma unroll
    for (int kt = 0; kt < NT; ++kt) {
        const int k0 = kt * BK;

        // Load this step's fragments straight from global (L1/L2-hit after
        // the first touch; no LDS, no barrier, no lockstep).
        float4 alo[4], ahi[4], blo[4], bhi[4];
#pragma unroll
        for (int m = 0; m < 4; ++m) {
            const float* p = Ab + (size_t)(m * 16) * DK + k0;
            alo[m] = *reinterpret_cast<const float4*>(p);
            ahi[m] = *reinterpret_cast<const float4*>(p + 4);
        }
#pragma unroll
        for (int n = 0; n < 4; ++n) {
            const float* p = Bb + (size_t)(n * 16) * DK + k0;
            blo[n] = *reinterpret_cast<const float4*>(p);
            bhi[n] = *reinterpret_cast<const float4*>(p + 4);
        }

        f16x8 af[4], bf[4];
#pragma unroll
        for (int m = 0; m < 4; ++m) af[m] = cvt8(alo[m], ahi[m]);
#pragma unroll
        for (int n = 0; n < 4; ++n) bf[n] = cvt8(blo[n], bhi[n]);

#pragma unroll
        for (int m = 0; m < 4; ++m)
#pragma unroll
            for (int n = 0; n < 4; ++n)
                acc[m][n] = __builtin_amdgcn_mfma_f32_16x16x32_f16(af[m], bf[n], acc[m][n], 0, 0, 0);
    }

    // Epilogue. C/D layout (m89/m91): col = lane&15, row = (lane>>4)*4 + reg.
    // Nontemporal: R8 proved allocating the 268MB write stream in L2 is -42us.
    float* Cb = C + (size_t)b * DM * DN;
    const int crow = brow + wr + (l >> 4) * 4;
    const int ccol = bcol + wc + lrow;
#pragma unroll
    for (int m = 0; m < 4; ++m)
#pragma unroll
        for (int j = 0; j < 4; ++j) {
            float* rowp = Cb + (size_t)(crow + m * 16 + j) * DN + ccol;
#pragma unroll
            for (int n = 0; n < 4; ++n)
                __builtin_nontemporal_store(acc[m][n][j], rowp + n * 16);
        }
}

extern "C" void kernel_launch(void* const* d_in, const int* in_sizes, int n_in,
                              void* d_out, int out_size, void* d_ws, size_t ws_size,
                              hipStream_t stream) {
    const float* m1 = (const float*)d_in[0];
    const float* m2 = (const float*)d_in[1];
    float* out = (float*)d_out;
    (void)d_ws; (void)ws_size;

    fused_gemm<<<NWG, 256, 0, stream>>>(m1, m2, out);
}

// Round 11
// 96.182 us; speedup vs baseline: 2.7518x; 2.7518x over previous
//
#include <hip/hip_runtime.h>
#include <hip/hip_bf16.h>
#include <stdint.h>

// Batched NT-GEMM: out[b,i,j] = sum_d m1[b,i,d] * m2[b,j,d]
// B=16, M=N=2048, K=256, fp32 in/out; f16 MFMA compute.
//
// Round 11: TLP attack. R9/R10 profiles: MfmaUtil 5-9%, VALUBusy 4-7%,
// occ 30-41% -> ~85% wait at 2 waves/SIMD. No pipe is saturated; the
// limiter is concurrency (lockstep barriers + block-end drains with no
// cover). Change: 512-thread blocks (8 waves), 32x64 per-wave tile:
//   acc 64->32 VGPR, staging 32->16, frags 32->24  => ~100 VGPR
//   -> 4-5 waves/SIMD (was 2). Single-depth staging (R7: depth tweaks
//   neutral; TLP now hides latency). Same LDS layout/swizzle/nt-stores.

typedef _Float16 f16x8 __attribute__((ext_vector_type(8)));
typedef _Float16 f16x4 __attribute__((ext_vector_type(4)));
typedef _Float16 f16x2 __attribute__((ext_vector_type(2)));
typedef float f32x4 __attribute__((ext_vector_type(4)));

#define NB 16
#define DM 2048
#define DN 2048
#define DK 256
#define BM 128
#define BN 128
#define BK 32
#define BKP 36                          // padded LDS row stride (elements)
#define NT (DK / BK)                    // 8 K-steps
#define NWG (NB * (DM/BM) * (DN/BN))    // 4096 blocks

// lgkm-only barrier: LDS writes published, VMEM ops stay outstanding.
#define LDS_BARRIER() do {                                   \
    asm volatile("s_waitcnt lgkmcnt(0)" ::: "memory");       \
    __builtin_amdgcn_s_barrier();                            \
    asm volatile("" ::: "memory");                           \
} while (0)

__global__ __launch_bounds__(512, 4) void fused_gemm(const float* __restrict__ A,
                                                     const float* __restrict__ B,
                                                     float* __restrict__ C) {
    __shared__ _Float16 As[2][BM * BKP];   // 9216 B per buffer
    __shared__ _Float16 Bs[2][BN * BKP];   // total 36 KB

    const int t = threadIdx.x;

    // XCD swizzle (NWG % 8 == 0 -> bijective); bx fastest within a chunk.
    const int bid = blockIdx.x;
    const int swz = (bid & 7) * (NWG / 8) + (bid >> 3);
    const int b    = swz >> 8;          // 256 blocks per batch
    const int rem  = swz & 255;
    const int brow = (rem >> 4) << 7;   // * BM
    const int bcol = (rem & 15) << 7;   // * BN

    const float* At = A + (size_t)b * DM * DK + (size_t)brow * DK;
    const float* Bt = B + (size_t)b * DN * DK + (size_t)bcol * DK;

    // 8 waves in a 4x2 grid: each wave owns a 32x64 output tile.
    const int w    = t >> 6;            // 0..7
    const int l    = t & 63;
    const int wrow = (w >> 1) * 32;     // wave row offset in tile
    const int wcol = (w & 1) * 64;      // wave col offset in tile
    const int lrow = l & 15;
    const int lko  = (l >> 4) * 8;      // k-offset of lane's 8 f16 elements

    f32x4 acc[2][4] = {};               // 2 m-frags x 4 n-frags = 32 VGPR

    // Staging: A tile = 128x32 fp32 = 1024 float4 chunks; 512 threads ->
    // 2 chunks each for A and for B: c = t + i*512, row r = c>>3, quad q = c&7.
    auto issue = [&](int kt, float4 (&va)[2], float4 (&vb)[2]) {
#pragma unroll
        for (int i = 0; i < 2; ++i) {
            const int c = t + i * 512;
            const int r = c >> 3, q = c & 7;
            va[i] = *reinterpret_cast<const float4*>(At + (size_t)r * DK + kt * BK + q * 4);
            vb[i] = *reinterpret_cast<const float4*>(Bt + (size_t)r * DK + kt * BK + q * 4);
        }
    };
    auto cvt4 = [](const float4& v) -> f16x4 {
        f16x2 lo = __builtin_bit_cast(f16x2, __builtin_amdgcn_cvt_pkrtz(v.x, v.y));
        f16x2 hi = __builtin_bit_cast(f16x2, __builtin_amdgcn_cvt_pkrtz(v.z, v.w));
        return f16x4{ lo[0], lo[1], hi[0], hi[1] };
    };
    auto wlds = [&](int buf, const float4 (&va)[2], const float4 (&vb)[2]) {
#pragma unroll
        for (int i = 0; i < 2; ++i) {
            const int c = t + i * 512;
            const int r = c >> 3, q = c & 7;
            *reinterpret_cast<f16x4*>(&As[buf][r * BKP + q * 4]) = cvt4(va[i]);
            *reinterpret_cast<f16x4*>(&Bs[buf][r * BKP + q * 4]) = cvt4(vb[i]);
        }
    };
    auto compute = [&](int buf) {
        f16x8 af[2], bf[4];
#pragma unroll
        for (int m = 0; m < 2; ++m)
            af[m] = *reinterpret_cast<const f16x8*>(&As[buf][(wrow + m * 16 + lrow) * BKP + lko]);
#pragma unroll
        for (int n = 0; n < 4; ++n)
            bf[n] = *reinterpret_cast<const f16x8*>(&Bs[buf][(wcol + n * 16 + lrow) * BKP + lko]);
#pragma unroll
        for (int m = 0; m < 2; ++m)
#pragma unroll
            for (int n = 0; n < 4; ++n)
                acc[m][n] = __builtin_amdgcn_mfma_f32_16x16x32_f16(af[m], bf[n], acc[m][n], 0, 0, 0);
    };

    // Single-depth staging registers (16 VGPR).
    float4 va[2], vb[2];

    // Prologue.
    issue(0, va, vb);
    wlds(0, va, vb);
    LDS_BARRIER();

    // Steady state: 1 barrier per K-step; dbuf alternates; TLP hides latency.
#pragma unroll
    for (int kt = 0; kt < NT; ++kt) {
        if (kt + 1 < NT) issue(kt + 1, va, vb);
        compute(kt & 1);
        if (kt + 1 < NT) wlds((kt + 1) & 1, va, vb);
        if (kt + 1 < NT) LDS_BARRIER();
    }

    // Epilogue. C/D layout (m89/m91): col = lane&15, row = (lane>>4)*4 + reg.
    // Nontemporal: R8 proved allocating the write stream in L2 costs +42us.
    float* Cb = C + (size_t)b * DM * DN;
    const int crow = brow + wrow + (l >> 4) * 4;
    const int ccol = bcol + wcol + lrow;
#pragma unroll
    for (int m = 0; m < 2; ++m)
#pragma unroll
        for (int j = 0; j < 4; ++j) {
            float* rowp = Cb + (size_t)(crow + m * 16 + j) * DN + ccol;
#pragma unroll
            for (int n = 0; n < 4; ++n)
                __builtin_nontemporal_store(acc[m][n][j], rowp + n * 16);
        }
}

extern "C" void kernel_launch(void* const* d_in, const int* in_sizes, int n_in,
                              void* d_out, int out_size, void* d_ws, size_t ws_size,
                              hipStream_t stream) {
    const float* m1 = (const float*)d_in[0];
    const float* m2 = (const float*)d_in[1];
    float* out = (float*)d_out;
    (void)d_ws; (void)ws_size;

    fused_gemm<<<NWG, 512, 0, stream>>>(m1, m2, out);
}

// Round 12
// 83.561 us; speedup vs baseline: 3.1674x; 1.1510x over previous
//
#include <hip/hip_runtime.h>
#include <hip/hip_bf16.h>
#include <stdint.h>

// Batched NT-GEMM: out[b,i,j] = sum_d m1[b,i,d] * m2[b,j,d]
// B=16, M=N=2048, K=256, fp32 in/out; f16 MFMA compute.
//
// Round 12: 2-tile persistent blocks + ping-pong accumulators.
//   Model (reproduces 75.8 exactly): per CU, 8 lockstep rounds of
//   {compute ~4us -> store-burst drain ~5.5us}, serialized. Fix: each block
//   computes TWO tiles (same A panel, bcol and bcol+128) in one flat 16-step
//   R7-style X/Y pipeline; tile-A's stores issue after its last MFMA, with
//   tile-B's first load batches already in flight (in-order vmcnt -> the
//   subsequent LDS waits gate on loads, only ~17 of 64 stores forced early),
//   and drain under tile-B's whole compute. acc0/acc1 are separate sets,
//   each written once -> NO re-zero, no WAR drain (R6's trap). No
//   sched_barrier. Grid 2048 (8 blocks/CU, 4 rounds, exposed drains 8->4).

typedef _Float16 f16x8 __attribute__((ext_vector_type(8)));
typedef _Float16 f16x4 __attribute__((ext_vector_type(4)));
typedef _Float16 f16x2 __attribute__((ext_vector_type(2)));
typedef float f32x4 __attribute__((ext_vector_type(4)));

#define NB 16
#define DM 2048
#define DN 2048
#define DK 256
#define BM 128
#define BN 128
#define BK 32
#define BKP 36                          // padded LDS row stride (elements)
#define NT (DK / BK)                    // 8 K-steps per tile
#define TSTEPS (2 * NT)                 // 16 pipeline steps (2 tiles)
#define NWG 2048                        // 16 b * 16 brow * 8 col-pairs

// lgkm-only barrier: LDS writes published, VMEM ops stay outstanding.
#define LDS_BARRIER() do {                                   \
    asm volatile("s_waitcnt lgkmcnt(0)" ::: "memory");       \
    __builtin_amdgcn_s_barrier();                            \
    asm volatile("" ::: "memory");                           \
} while (0)

__global__ __launch_bounds__(256, 2) void fused_gemm(const float* __restrict__ A,
                                                     const float* __restrict__ B,
                                                     float* __restrict__ C) {
    __shared__ _Float16 As[2][BM * BKP];   // 9216 B per buffer
    __shared__ _Float16 Bs[2][BN * BKP];

    const int t = threadIdx.x;

    // XCD swizzle (2048 % 8 == 0 -> bijective); col-pair fastest in a chunk.
    const int bid = blockIdx.x;
    const int swz = (bid & 7) * (NWG / 8) + (bid >> 3);
    const int b    = swz >> 7;          // 128 blocks per batch
    const int rem  = swz & 127;
    const int brow = (rem >> 3) << 7;   // * BM
    const int bcol = (rem & 7) << 8;    // * 2*BN (this block owns bcol, bcol+128)

    const float* At  = A + (size_t)b * DM * DK + (size_t)brow * DK;
    const float* Bt0 = B + (size_t)b * DN * DK + (size_t)bcol * DK;

    const int w    = t >> 6;
    const int l    = t & 63;
    const int wr   = (w >> 1) * 64;     // wave row offset in tile
    const int wc   = (w & 1) * 64;      // wave col offset in tile
    const int lrow = l & 15;
    const int lko  = (l >> 4) * 8;      // k-offset of lane's 8 f16 elements

    f32x4 acc0[4][4] = {};              // tile 0 accumulator (written once)
    f32x4 acc1[4][4] = {};              // tile 1 accumulator (written once)

    // Staging: tile-step = 128 rows x 32 k fp32 = 1024 float4 chunks;
    // thread t owns chunks c = t + i*256 -> row r = c>>3, quad q = c&7.
    // Step s: tile = s>>3 (B pointer offset), kt = s&7. s is compile-time
    // constant in the fully-unrolled loop.
    auto issue = [&](int s, float4 (&va)[4], float4 (&vb)[4]) {
        const float* Ap = At + (size_t)(s & 7) * BK;
        const float* Bp = Bt0 + (size_t)(s >> 3) * BN * DK + (size_t)(s & 7) * BK;
#pragma unroll
        for (int i = 0; i < 4; ++i) {
            const int c = t + i * 256;
            const int r = c >> 3, q = c & 7;
            va[i] = *reinterpret_cast<const float4*>(Ap + (size_t)r * DK + q * 4);
            vb[i] = *reinterpret_cast<const float4*>(Bp + (size_t)r * DK + q * 4);
        }
    };
    auto cvt4 = [](const float4& v) -> f16x4 {
        f16x2 lo = __builtin_bit_cast(f16x2, __builtin_amdgcn_cvt_pkrtz(v.x, v.y));
        f16x2 hi = __builtin_bit_cast(f16x2, __builtin_amdgcn_cvt_pkrtz(v.z, v.w));
        return f16x4{ lo[0], lo[1], hi[0], hi[1] };
    };
    auto wlds = [&](int buf, const float4 (&va)[4], const float4 (&vb)[4]) {
#pragma unroll
        for (int i = 0; i < 4; ++i) {
            const int c = t + i * 256;
            const int r = c >> 3, q = c & 7;
            *reinterpret_cast<f16x4*>(&As[buf][r * BKP + q * 4]) = cvt4(va[i]);
            *reinterpret_cast<f16x4*>(&Bs[buf][r * BKP + q * 4]) = cvt4(vb[i]);
        }
    };
    auto compute = [&](int buf, f32x4 (&acc)[4][4]) {
        f16x8 af[4], bf[4];
#pragma unroll
        for (int m = 0; m < 4; ++m)
            af[m] = *reinterpret_cast<const f16x8*>(&As[buf][(wr + m * 16 + lrow) * BKP + lko]);
#pragma unroll
        for (int n = 0; n < 4; ++n)
            bf[n] = *reinterpret_cast<const f16x8*>(&Bs[buf][(wc + n * 16 + lrow) * BKP + lko]);
#pragma unroll
        for (int m = 0; m < 4; ++m)
#pragma unroll
            for (int n = 0; n < 4; ++n)
                acc[m][n] = __builtin_amdgcn_mfma_f32_16x16x32_f16(af[m], bf[n], acc[m][n], 0, 0, 0);
    };

    // Epilogue stores. C/D layout (m89/m91): col=lane&15, row=(lane>>4)*4+reg.
    // Nontemporal: R8 proved allocating the write stream in L2 costs +42us.
    float* Cb = C + (size_t)b * DM * DN;
    const int crow = brow + wr + (l >> 4) * 4;
    auto store_tile = [&](int tile, const f32x4 (&acc)[4][4]) {
        const int ccol = bcol + tile * BN + wc + lrow;
#pragma unroll
        for (int m = 0; m < 4; ++m)
#pragma unroll
            for (int j = 0; j < 4; ++j) {
                float* rowp = Cb + (size_t)(crow + m * 16 + j) * DN + ccol;
#pragma unroll
                for (int n = 0; n < 4; ++n)
                    __builtin_nontemporal_store(acc[m][n][j], rowp + n * 16);
            }
    };

    // Two named in-flight register sets (static indexing only - rule #20).
    float4 vaX[4], vbX[4], vaY[4], vbY[4];

    // Prologue: steps 0 (X) and 1 (Y) in flight; write step 0 -> buf0.
    issue(0, vaX, vbX);
    issue(1, vaY, vbY);
    wlds(0, vaX, vbX);        // counted wait: Y's loads stay outstanding
    LDS_BARRIER();

    // Flat 16-step pipeline, 2 steps per iteration; fully unrolled so the
    // tile index (s>>3) and acc selection are compile-time static.
#pragma unroll
    for (int s2 = 0; s2 < TSTEPS; s2 += 2) {
        if (s2 + 2 < TSTEPS) issue(s2 + 2, vaX, vbX);
        if (s2 < NT) compute(0, acc0); else compute(0, acc1);
        wlds(1, vaY, vbY);                 // step s2+1 (TSTEPS even -> exists)
        LDS_BARRIER();

        if (s2 + 3 < TSTEPS) issue(s2 + 3, vaY, vbY);
        if (s2 + 1 < NT) compute(1, acc0); else compute(1, acc1);

        if (s2 + 1 == NT - 1) {
            // Tile 0 complete (step 7). Tile-1's first two load batches
            // (steps 8,9) are already in flight, issued BEFORE these stores:
            // upcoming LDS waits gate on those loads; the stores drain
            // under tile-1's entire compute.
            store_tile(0, acc0);
        }

        if (s2 + 2 < TSTEPS) wlds(0, vaX, vbX);
        LDS_BARRIER();
    }

    store_tile(1, acc1);
}

extern "C" void kernel_launch(void* const* d_in, const int* in_sizes, int n_in,
                              void* d_out, int out_size, void* d_ws, size_t ws_size,
                              hipStream_t stream) {
    const float* m1 = (const float*)d_in[0];
    const float* m2 = (const float*)d_in[1];
    float* out = (float*)d_out;
    (void)d_ws; (void)ws_size;

    fused_gemm<<<NWG, 256, 0, stream>>>(m1, m2, out);
}